// Round 4
// baseline (1491.985 us; speedup 1.0000x reference)
//
#include <hip/hip_runtime.h>
#include <hip/hip_fp16.h>
#include <math.h>

#define N_NODES 50000
#define E_EDGES 800000
#define E_TOT   850000   // E + N self loops
#define HC 128
#define NHEAD 4
#define LIN 256
#define OUTC 10
#define NG 64
#define NEG_SLOPE 0.2f

// src-tiling for L2-resident gathers (R15): 5 tiles x 10000 nodes
// tile footprint = 10000 * 256B = 2.56 MB < 4 MiB per-XCD L2 (+ 800KB asrc)
#define NT 5
#define TILE_N 10000
#define NSEG (N_NODES * NT)     // 250000 (dst,tile) segments
#define NWAVE 4096              // 1024 blocks x 4 waves, all co-resident
#define NPW 13                  // nodes per wave: 4096*13 >= 50000

__device__ __forceinline__ float lrelu(float v) { return v > 0.f ? v : NEG_SLOPE * v; }

typedef _Float16 half8v __attribute__((ext_vector_type(8)));
typedef float    float4v __attribute__((ext_vector_type(4)));

// ---------------------------------------------------------------------------
// MFMA GEMM + attention logits (unchanged from the 551us baseline).
// ---------------------------------------------------------------------------
__global__ __launch_bounds__(256) void k_gemm_mfma(
    const float* __restrict__ x, const float* __restrict__ W,
    const float* __restrict__ a_s, const float* __restrict__ a_d,
    __half* __restrict__ h, float* __restrict__ asrc, float* __restrict__ adst) {
  __shared__ _Float16 Wt[128 * 136];       // W^T fp16, padded row stride 136
  __shared__ _Float16 hst[4][16][136];     // per-wave C staging (padded)
  __shared__ float aS[HC], aD[HC];
  int tid = threadIdx.x;
  if (tid < HC) { aS[tid] = a_s[tid]; aD[tid] = a_d[tid]; }
  for (int i = 0; i < 64; i++) {
    int idx = tid + i * 256;               // 16384 elements
    int k = idx >> 7, n = idx & 127;
    Wt[n * 136 + k] = (_Float16)W[idx];
  }
  __syncthreads();

  int wv = tid >> 6, lane = tid & 63;
  int quad = lane >> 4, low = lane & 15;
  int rowbase = blockIdx.x * 64 + wv * 16;
  int row = rowbase + low;
  int rowc = row < N_NODES ? row : N_NODES - 1;  // clamp; stores guarded

  float4v acc[8];
#pragma unroll
  for (int t = 0; t < 8; t++) acc[t] = (float4v){0.f, 0.f, 0.f, 0.f};

#pragma unroll
  for (int k4 = 0; k4 < 4; k4++) {
    int kb = k4 * 32 + quad * 8;
    float4 xa = *(const float4*)(x + (size_t)rowc * HC + kb);
    float4 xb = *(const float4*)(x + (size_t)rowc * HC + kb + 4);
    half8v af;
    af[0] = (_Float16)xa.x; af[1] = (_Float16)xa.y;
    af[2] = (_Float16)xa.z; af[3] = (_Float16)xa.w;
    af[4] = (_Float16)xb.x; af[5] = (_Float16)xb.y;
    af[6] = (_Float16)xb.z; af[7] = (_Float16)xb.w;
    half8v bf[8];
#pragma unroll
    for (int t = 0; t < 8; t++)
      bf[t] = *(const half8v*)&Wt[(t * 16 + low) * 136 + kb];
#pragma unroll
    for (int t = 0; t < 8; t++)
      acc[t] = __builtin_amdgcn_mfma_f32_16x16x32_f16(af, bf[t], acc[t], 0, 0, 0);
  }

#pragma unroll
  for (int t = 0; t < 8; t++)
#pragma unroll
    for (int r = 0; r < 4; r++)
      hst[wv][quad * 4 + r][t * 16 + low] = (_Float16)acc[t][r];
  __syncthreads();

  {
    int r = lane >> 2, part = lane & 3;
    int grow = rowbase + r;
    if (grow < N_NODES) {
      const float4* src = (const float4*)&hst[wv][r][part * 32];
      float4* dst = (float4*)(h + (size_t)grow * HC + part * 32);
#pragma unroll
      for (int i = 0; i < 4; i++) dst[i] = src[i];
    }
  }
  {
    int grow = rowbase + low;
    float ss = 0.f, dd = 0.f;
#pragma unroll
    for (int i = 0; i < 32; i++) {
      float hv = (float)hst[wv][low][quad * 32 + i];
      ss += hv * aS[quad * 32 + i];
      dd += hv * aD[quad * 32 + i];
    }
    if (grow < N_NODES) {
      asrc[grow * NHEAD + quad] = ss;
      adst[grow * NHEAD + quad] = dd;
    }
  }
}

// ---------------------------------------------------------------------------
// CSR build, counting-sorted by (dst, src_tile):
// histogram over 250k (dst,tile) cells -> scan -> scatter
// ---------------------------------------------------------------------------
__global__ __launch_bounds__(256) void k_hist(
    const int* __restrict__ dst, const int* __restrict__ src,
    int* __restrict__ degT) {
  int e = blockIdx.x * 256 + threadIdx.x;
  if (e >= E_TOT) return;
  int d, s;
  if (e < E_EDGES) { d = dst[e]; s = src[e]; } else { d = s = e - E_EDGES; }
  int t = s / TILE_N;
  atomicAdd(&degT[d * NT + t], 1);
}

__global__ __launch_bounds__(1024) void k_scan(
    const int* __restrict__ degT, int* __restrict__ offT,
    unsigned* __restrict__ pooled) {
  // fold the pooled zeroing in here (saves one dispatch)
  if (threadIdx.x < NG * HC / 8) {
    ((uint2*)pooled)[threadIdx.x * 4 + 0] = make_uint2(0u, 0u);
    ((uint2*)pooled)[threadIdx.x * 4 + 1] = make_uint2(0u, 0u);
    ((uint2*)pooled)[threadIdx.x * 4 + 2] = make_uint2(0u, 0u);
    ((uint2*)pooled)[threadIdx.x * 4 + 3] = make_uint2(0u, 0u);
  }
  __shared__ int ps[1024];
  int tid = threadIdx.x;
  const int CH = (NSEG + 1023) / 1024;  // 245
  int base = tid * CH;
  int sum = 0;
  for (int i = 0; i < CH; i++) {
    int idx = base + i;
    if (idx < NSEG) sum += degT[idx];
  }
  ps[tid] = sum;
  __syncthreads();
  for (int off = 1; off < 1024; off <<= 1) {
    int v = (tid >= off) ? ps[tid - off] : 0;
    __syncthreads();
    ps[tid] += v;
    __syncthreads();
  }
  int run = (tid ? ps[tid - 1] : 0);
  for (int i = 0; i < CH; i++) {
    int idx = base + i;
    if (idx < NSEG) { offT[idx] = run; run += degT[idx]; }
  }
  if (tid == 1023) offT[NSEG] = run;
}

__global__ __launch_bounds__(256) void k_scatter(
    const int* __restrict__ src, const int* __restrict__ dst,
    const int* __restrict__ offT, int* __restrict__ cntT,
    int* __restrict__ csr_src) {
  int e = blockIdx.x * 256 + threadIdx.x;
  if (e >= E_TOT) return;
  int s, d;
  if (e < E_EDGES) { s = src[e]; d = dst[e]; } else { s = d = e - E_EDGES; }
  int t = s / TILE_N;
  int pos = offT[d * NT + t] + atomicAdd(&cntT[d * NT + t], 1);
  csr_src[pos] = s;
}

#define BFLY_MAX4(m0, m1, m2, m3)                         \
  _Pragma("unroll") for (int off = 1; off < 64; off <<= 1) { \
    m0 = fmaxf(m0, __shfl_xor(m0, off));                  \
    m1 = fmaxf(m1, __shfl_xor(m1, off));                  \
    m2 = fmaxf(m2, __shfl_xor(m2, off));                  \
    m3 = fmaxf(m3, __shfl_xor(m3, off));                  \
  }
#define BFLY_SUM4(s0, s1, s2, s3)                         \
  _Pragma("unroll") for (int off = 1; off < 64; off <<= 1) { \
    s0 += __shfl_xor(s0, off);                            \
    s1 += __shfl_xor(s1, off);                            \
    s2 += __shfl_xor(s2, off);                            \
    s3 += __shfl_xor(s3, off);                            \
  }

// ---------------------------------------------------------------------------
// R15: src-tiled persistent aggregation.
// Theory (validated on V_old/R2/R3): gather throughput = per-CU MSHR
// (~32 lines) x miss latency. All-miss (900cy, L3): 13.3k lines/CU -> 156us
// (matches 151 measured). Fix: make misses L2 hits via src-tiling.
// Grid = 1024 blocks (all resident, 16 waves/CU). Wave owns NPW=13 nodes
// (node = wid + 4096*k). Phase 0: softmax stats per node (asrc-only; m,
// 1/S, adst kept per-lane-head in regs). Phase 1: for tile t (barrier per
// block between tiles): for each node: scan its (dst,t) segment, recompute
// w = exp(lrelu(asrc[sv][hc]+adh)-m) from L2-resident asrc (800KB), gather
// h[sv] row (one 256B span per instr -- LAW R5/R7/R10), accumulate in regs.
// No LDS, no cross-pass accumulator traffic.
// ---------------------------------------------------------------------------
__global__ __launch_bounds__(256, 4) void k_aggr(
    const int* __restrict__ offT, const int* __restrict__ csr_src,
    const float* __restrict__ asrc, const float* __restrict__ adst,
    const __half* __restrict__ h, const float* __restrict__ bias,
    const int* __restrict__ batch, float* __restrict__ out_h,
    unsigned* __restrict__ pooled, int do_pool) {
  int tid = threadIdx.x;
  int wv = tid >> 6, lane = tid & 63;
  int wid = blockIdx.x * 4 + wv;           // 0..4095
  int hc = lane >> 4;                      // head for this lane's 2 feats

  float m_[NPW], rd_[NPW], adh_[NPW], ax_[NPW], ay_[NPW];

  // ---- phase 0: softmax stats per node (no h traffic) ----
#pragma unroll
  for (int k = 0; k < NPW; k++) {
    m_[k] = 0.f; rd_[k] = 0.f; adh_[k] = 0.f; ax_[k] = 0.f; ay_[k] = 0.f;
    int node = wid + NWAVE * k;
    if (node < N_NODES) {
      int flo = offT[node * NT], fhi = offT[node * NT + NT];
      int deg = fhi - flo;
      float4 ad4 = ((const float4*)adst)[node];
      adh_[k] = (hc == 0) ? ad4.x : (hc == 1) ? ad4.y : (hc == 2) ? ad4.z : ad4.w;
      if (deg <= 64) {
        int j = flo + lane;
        bool valid = j < fhi;
        int sv = valid ? csr_src[j] : 0;
        float4 a4 = ((const float4*)asrc)[sv];
        float e0 = valid ? lrelu(a4.x + ad4.x) : -1e30f;
        float e1 = valid ? lrelu(a4.y + ad4.y) : -1e30f;
        float e2 = valid ? lrelu(a4.z + ad4.z) : -1e30f;
        float e3 = valid ? lrelu(a4.w + ad4.w) : -1e30f;
        float m0 = e0, m1 = e1, m2 = e2, m3 = e3;
        BFLY_MAX4(m0, m1, m2, m3)
        float w0 = expf(e0 - m0), w1 = expf(e1 - m1);
        float w2 = expf(e2 - m2), w3 = expf(e3 - m3);
        float s0 = w0, s1 = w1, s2 = w2, s3 = w3;
        BFLY_SUM4(s0, s1, s2, s3)
        m_[k] = (hc == 0) ? m0 : (hc == 1) ? m1 : (hc == 2) ? m2 : m3;
        float S = (hc == 0) ? s0 : (hc == 1) ? s1 : (hc == 2) ? s2 : s3;
        rd_[k] = 1.f / S;
      } else {
        float M0 = -1e30f, M1 = -1e30f, M2 = -1e30f, M3 = -1e30f;
        for (int c = flo; c < fhi; c += 64) {
          int j = c + lane;
          bool valid = j < fhi;
          int sv = valid ? csr_src[j] : 0;
          float4 a4 = ((const float4*)asrc)[sv];
          float e0 = valid ? lrelu(a4.x + ad4.x) : -1e30f;
          float e1 = valid ? lrelu(a4.y + ad4.y) : -1e30f;
          float e2 = valid ? lrelu(a4.z + ad4.z) : -1e30f;
          float e3 = valid ? lrelu(a4.w + ad4.w) : -1e30f;
          BFLY_MAX4(e0, e1, e2, e3)
          M0 = fmaxf(M0, e0); M1 = fmaxf(M1, e1);
          M2 = fmaxf(M2, e2); M3 = fmaxf(M3, e3);
        }
        float S0 = 0.f, S1 = 0.f, S2 = 0.f, S3 = 0.f;
        for (int c = flo; c < fhi; c += 64) {
          int j = c + lane;
          bool valid = j < fhi;
          int sv = valid ? csr_src[j] : 0;
          float4 a4 = ((const float4*)asrc)[sv];
          float e0 = valid ? lrelu(a4.x + ad4.x) : -1e30f;
          float e1 = valid ? lrelu(a4.y + ad4.y) : -1e30f;
          float e2 = valid ? lrelu(a4.z + ad4.z) : -1e30f;
          float e3 = valid ? lrelu(a4.w + ad4.w) : -1e30f;
          float w0 = expf(e0 - M0), w1 = expf(e1 - M1);
          float w2 = expf(e2 - M2), w3 = expf(e3 - M3);
          float s0 = w0, s1 = w1, s2 = w2, s3 = w3;
          BFLY_SUM4(s0, s1, s2, s3)
          S0 += s0; S1 += s1; S2 += s2; S3 += s3;
        }
        m_[k] = (hc == 0) ? M0 : (hc == 1) ? M1 : (hc == 2) ? M2 : M3;
        float S = (hc == 0) ? S0 : (hc == 1) ? S1 : (hc == 2) ? S2 : S3;
        rd_[k] = 1.f / S;
      }
    }
  }

  // ---- phase 1: tile sweep (L2-resident gathers) ----
  for (int t = 0; t < NT; t++) {
#pragma unroll
    for (int k = 0; k < NPW; k++) {
      int node = wid + NWAVE * k;
      if (node >= N_NODES) continue;
      int s0 = offT[node * NT + t], s1 = offT[node * NT + t + 1];
      float adh = adh_[k], mk = m_[k];
      float ax = 0.f, ay = 0.f;
      for (int j = s0; j < s1; j += 4) {
        int jb = j + 1 < s1 ? j + 1 : s1 - 1;
        int jc = j + 2 < s1 ? j + 2 : s1 - 1;
        int jd = j + 3 < s1 ? j + 3 : s1 - 1;
        bool vb = j + 1 < s1, vc = j + 2 < s1, vd = j + 3 < s1;
        int sa = csr_src[j],  sb = csr_src[jb];
        int sc = csr_src[jc], sd = csr_src[jd];
        float Aa = asrc[sa * NHEAD + hc], Ab = asrc[sb * NHEAD + hc];
        float Ac = asrc[sc * NHEAD + hc], Ad = asrc[sd * NHEAD + hc];
        float2 Ha = __half22float2(*(const __half2*)(h + (size_t)sa * HC + lane * 2));
        float2 Hb = __half22float2(*(const __half2*)(h + (size_t)sb * HC + lane * 2));
        float2 Hc = __half22float2(*(const __half2*)(h + (size_t)sc * HC + lane * 2));
        float2 Hd = __half22float2(*(const __half2*)(h + (size_t)sd * HC + lane * 2));
        float wa = expf(lrelu(Aa + adh) - mk);
        float wb = vb ? expf(lrelu(Ab + adh) - mk) : 0.f;
        float wc = vc ? expf(lrelu(Ac + adh) - mk) : 0.f;
        float wd = vd ? expf(lrelu(Ad + adh) - mk) : 0.f;
        ax += wa * Ha.x + wb * Hb.x + wc * Hc.x + wd * Hd.x;
        ay += wa * Ha.y + wb * Hb.y + wc * Hc.y + wd * Hd.y;
      }
      ax_[k] += ax; ay_[k] += ay;
    }
    __syncthreads();   // intra-block tile coherence (all waves present)
  }

  // ---- epilogue: normalize, bias, relu, store (+pool) ----
  float2 b = *(const float2*)(bias + lane * 2);
#pragma unroll
  for (int k = 0; k < NPW; k++) {
    int node = wid + NWAVE * k;
    if (node >= N_NODES) continue;
    float vx = fmaxf(ax_[k] * rd_[k] + b.x, 0.f);
    float vy = fmaxf(ay_[k] * rd_[k] + b.y, 0.f);
    *(float2*)(out_h + (size_t)node * HC + lane * 2) = make_float2(vx, vy);
    if (do_pool) {
      int g = batch[node];
      unsigned* pp = pooled + g * HC + lane * 2;
      // post-relu values >= 0: bit compare == float compare; init 0 matches
      // the reference's where(isfinite, pooled, 0) empty-graph guard.
      atomicMax(pp + 0, __float_as_uint(vx));
      atomicMax(pp + 1, __float_as_uint(vy));
    }
  }
}

// final head: out[g] = (pooled[g] @ Wlin + blin) @ Wout + bout ; 1 block/graph
__global__ __launch_bounds__(256) void k_mlp(
    const float* __restrict__ pooled, const float* __restrict__ Wlin,
    const float* __restrict__ blin, const float* __restrict__ Wout,
    const float* __restrict__ bout, float* __restrict__ out) {
  __shared__ float p[HC];
  __shared__ float z[LIN];
  int g = blockIdx.x, tid = threadIdx.x;
  if (tid < HC) p[tid] = pooled[g * HC + tid];
  __syncthreads();
  float zv = blin[tid];
  for (int k = 0; k < HC; k++) zv += p[k] * Wlin[k * LIN + tid];
  z[tid] = zv;
  __syncthreads();
  if (tid < OUTC) {
    float o = bout[tid];
    for (int k = 0; k < LIN; k++) o += z[k] * Wout[k * OUTC + tid];
    out[g * OUTC + tid] = o;
  }
}

extern "C" void kernel_launch(void* const* d_in, const int* in_sizes, int n_in,
                              void* d_out, int out_size, void* d_ws, size_t ws_size,
                              hipStream_t stream) {
  const float* x     = (const float*)d_in[0];
  const int*   ei    = (const int*)d_in[1];
  const int*   batch = (const int*)d_in[2];
  const float* Wl[3] = {(const float*)d_in[3], (const float*)d_in[7], (const float*)d_in[11]};
  const float* As[3] = {(const float*)d_in[4], (const float*)d_in[8], (const float*)d_in[12]};
  const float* Ad[3] = {(const float*)d_in[5], (const float*)d_in[9], (const float*)d_in[13]};
  const float* Bi[3] = {(const float*)d_in[6], (const float*)d_in[10], (const float*)d_in[14]};
  const float* Wlin  = (const float*)d_in[15];
  const float* blin  = (const float*)d_in[16];
  const float* Wout  = (const float*)d_in[17];
  const float* bout  = (const float*)d_in[18];
  float* out = (float*)d_out;

  // workspace layout (float offsets), packed tighter than baseline (46.4MB):
  float* ws = (float*)d_ws;
  __half*   h       = (__half*)ws;                 // N*128 halves (3.2M fl)
  float*    nodeB   = ws + 3200000;                // N*128 fp32   (6.4M fl)
  float*    asrc    = ws + 9600000;                // N*4
  float*    adst    = ws + 9800000;                // N*4
  int*      degT    = (int*)(ws + 10000000);       // 250k (adjacent to cntT)
  int*      cntT    = (int*)(ws + 10250000);       // 250k
  int*      offT    = (int*)(ws + 10500000);       // 250001
  int*      csr_src = (int*)(ws + 10750004);       // E_TOT (+pad)
  unsigned* pooled  = (unsigned*)(ws + 11600008);  // 64*128

  const int* srcp = ei;
  const int* dstp = ei + E_EDGES;

  hipMemsetAsync(degT, 0, 2 * NSEG * sizeof(int), stream);  // degT + cntT

  // (dst, src_tile)-sorted CSR — built once, reused by all 3 layers
  k_hist<<<(E_TOT + 255) / 256, 256, 0, stream>>>(dstp, srcp, degT);
  k_scan<<<1, 1024, 0, stream>>>(degT, offT, pooled);
  k_scatter<<<(E_TOT + 255) / 256, 256, 0, stream>>>(srcp, dstp, offT, cntT, csr_src);

  const float* lin_in = x;
  for (int L = 0; L < 3; L++) {
    k_gemm_mfma<<<(N_NODES + 63) / 64, 256, 0, stream>>>(
        lin_in, Wl[L], As[L], Ad[L], h, asrc, adst);
    k_aggr<<<NWAVE / 4, 256, 0, stream>>>(
        offT, csr_src, asrc, adst, h, Bi[L], batch,
        nodeB, pooled, (L == 2) ? 1 : 0);
    lin_in = nodeB;
  }
  k_mlp<<<NG, 256, 0, stream>>>((const float*)pooled, Wlin, blin, Wout, bout, out);
}

// Round 5
// 508.303 us; speedup vs baseline: 2.9352x; 2.9352x over previous
//
#include <hip/hip_runtime.h>
#include <hip/hip_fp16.h>
#include <math.h>

#define N_NODES 50000
#define E_EDGES 800000
#define E_TOT   850000   // E + N self loops
#define HC 128
#define NHEAD 4
#define LIN 256
#define OUTC 10
#define NG 64
#define NEG_SLOPE 0.2f

// (dst, src-tile)-sorted CSR (R16): edges of each node are contiguous and
// tile-ordered; V_old aggr consumes [offT[n*NT], offT[(n+1)*NT]) unchanged.
#define NT 5
#define TILE_N 10000
#define NSEG (N_NODES * NT)     // 250000 (dst,tile) cells
#define SCAN_BLOCKS 245         // 245 * 1024 cells >= NSEG

__device__ __forceinline__ float lrelu(float v) { return v > 0.f ? v : NEG_SLOPE * v; }

typedef _Float16 half8v __attribute__((ext_vector_type(8)));
typedef float    float4v __attribute__((ext_vector_type(4)));

// ---------------------------------------------------------------------------
// MFMA GEMM + attention logits (unchanged from the 551us baseline).
// ---------------------------------------------------------------------------
__global__ __launch_bounds__(256) void k_gemm_mfma(
    const float* __restrict__ x, const float* __restrict__ W,
    const float* __restrict__ a_s, const float* __restrict__ a_d,
    __half* __restrict__ h, float* __restrict__ asrc, float* __restrict__ adst) {
  __shared__ _Float16 Wt[128 * 136];       // W^T fp16, padded row stride 136
  __shared__ _Float16 hst[4][16][136];     // per-wave C staging (padded)
  __shared__ float aS[HC], aD[HC];
  int tid = threadIdx.x;
  if (tid < HC) { aS[tid] = a_s[tid]; aD[tid] = a_d[tid]; }
  for (int i = 0; i < 64; i++) {
    int idx = tid + i * 256;               // 16384 elements
    int k = idx >> 7, n = idx & 127;
    Wt[n * 136 + k] = (_Float16)W[idx];
  }
  __syncthreads();

  int wv = tid >> 6, lane = tid & 63;
  int quad = lane >> 4, low = lane & 15;
  int rowbase = blockIdx.x * 64 + wv * 16;
  int row = rowbase + low;
  int rowc = row < N_NODES ? row : N_NODES - 1;  // clamp; stores guarded

  float4v acc[8];
#pragma unroll
  for (int t = 0; t < 8; t++) acc[t] = (float4v){0.f, 0.f, 0.f, 0.f};

#pragma unroll
  for (int k4 = 0; k4 < 4; k4++) {
    int kb = k4 * 32 + quad * 8;
    float4 xa = *(const float4*)(x + (size_t)rowc * HC + kb);
    float4 xb = *(const float4*)(x + (size_t)rowc * HC + kb + 4);
    half8v af;
    af[0] = (_Float16)xa.x; af[1] = (_Float16)xa.y;
    af[2] = (_Float16)xa.z; af[3] = (_Float16)xa.w;
    af[4] = (_Float16)xb.x; af[5] = (_Float16)xb.y;
    af[6] = (_Float16)xb.z; af[7] = (_Float16)xb.w;
    half8v bf[8];
#pragma unroll
    for (int t = 0; t < 8; t++)
      bf[t] = *(const half8v*)&Wt[(t * 16 + low) * 136 + kb];
#pragma unroll
    for (int t = 0; t < 8; t++)
      acc[t] = __builtin_amdgcn_mfma_f32_16x16x32_f16(af, bf[t], acc[t], 0, 0, 0);
  }

#pragma unroll
  for (int t = 0; t < 8; t++)
#pragma unroll
    for (int r = 0; r < 4; r++)
      hst[wv][quad * 4 + r][t * 16 + low] = (_Float16)acc[t][r];
  __syncthreads();

  {
    int r = lane >> 2, part = lane & 3;
    int grow = rowbase + r;
    if (grow < N_NODES) {
      const float4* src = (const float4*)&hst[wv][r][part * 32];
      float4* dst = (float4*)(h + (size_t)grow * HC + part * 32);
#pragma unroll
      for (int i = 0; i < 4; i++) dst[i] = src[i];
    }
  }
  {
    int grow = rowbase + low;
    float ss = 0.f, dd = 0.f;
#pragma unroll
    for (int i = 0; i < 32; i++) {
      float hv = (float)hst[wv][low][quad * 32 + i];
      ss += hv * aS[quad * 32 + i];
      dd += hv * aD[quad * 32 + i];
    }
    if (grow < N_NODES) {
      asrc[grow * NHEAD + quad] = ss;
      adst[grow * NHEAD + quad] = dd;
    }
  }
}

// ---------------------------------------------------------------------------
// CSR build, counting-sorted by (dst, src_tile). Scan is hierarchical
// (R16: the R15 single-block scan over 250k cells was 520us of one CU).
// ---------------------------------------------------------------------------
__global__ __launch_bounds__(256) void k_hist(
    const int* __restrict__ dst, const int* __restrict__ src,
    int* __restrict__ degT) {
  int e = blockIdx.x * 256 + threadIdx.x;
  if (e >= E_TOT) return;
  int d, s;
  if (e < E_EDGES) { d = dst[e]; s = src[e]; } else { d = s = e - E_EDGES; }
  int t = s / TILE_N;
  atomicAdd(&degT[d * NT + t], 1);
}

// scanA: per-block (1024-cell chunk) sums
__global__ __launch_bounds__(256) void k_scanA(
    const int* __restrict__ degT, int* __restrict__ bsum) {
  __shared__ int ps[256];
  int tid = threadIdx.x, b = blockIdx.x;
  int base = b * 1024 + tid * 4;
  int s = 0;
#pragma unroll
  for (int i = 0; i < 4; i++) {
    int idx = base + i;
    if (idx < NSEG) s += degT[idx];
  }
  ps[tid] = s;
  __syncthreads();
  for (int off = 128; off > 0; off >>= 1) {
    if (tid < off) ps[tid] += ps[tid + off];
    __syncthreads();
  }
  if (tid == 0) bsum[b] = ps[0];
}

// scanB: exclusive scan of the 245 block sums (+ pooled zeroing folded in)
__global__ __launch_bounds__(256) void k_scanB(
    const int* __restrict__ bsum, int* __restrict__ boff,
    unsigned* __restrict__ pooled) {
  __shared__ int ps[256];
  int tid = threadIdx.x;
  // zero pooled: 64*128 uints = 32KB; each thread 8x uint4
  {
    uint4* p4 = (uint4*)pooled;
#pragma unroll
    for (int i = 0; i < 8; i++) p4[tid * 8 + i] = make_uint4(0u, 0u, 0u, 0u);
  }
  int s = (tid < SCAN_BLOCKS) ? bsum[tid] : 0;
  ps[tid] = s;
  __syncthreads();
  for (int off = 1; off < 256; off <<= 1) {
    int v = (tid >= off) ? ps[tid - off] : 0;
    __syncthreads();
    ps[tid] += v;
    __syncthreads();
  }
  if (tid < SCAN_BLOCKS) boff[tid] = ps[tid] - s;  // exclusive
}

// scanC: re-scan chunks with block offset, write offT (+ final total)
__global__ __launch_bounds__(256) void k_scanC(
    const int* __restrict__ degT, const int* __restrict__ boff,
    int* __restrict__ offT) {
  __shared__ int ps[256];
  int tid = threadIdx.x, b = blockIdx.x;
  int base = b * 1024 + tid * 4;
  int d[4];
  int s = 0;
#pragma unroll
  for (int i = 0; i < 4; i++) {
    int idx = base + i;
    d[i] = (idx < NSEG) ? degT[idx] : 0;
    s += d[i];
  }
  ps[tid] = s;
  __syncthreads();
  for (int off = 1; off < 256; off <<= 1) {
    int v = (tid >= off) ? ps[tid - off] : 0;
    __syncthreads();
    ps[tid] += v;
    __syncthreads();
  }
  int run = boff[b] + ps[tid] - s;  // exclusive prefix for this thread's cells
#pragma unroll
  for (int i = 0; i < 4; i++) {
    int idx = base + i;
    if (idx < NSEG) {
      offT[idx] = run;
      run += d[i];
      if (idx == NSEG - 1) offT[NSEG] = run;
    }
  }
}

__global__ __launch_bounds__(256) void k_scatter(
    const int* __restrict__ src, const int* __restrict__ dst,
    const int* __restrict__ offT, int* __restrict__ cntT,
    int* __restrict__ csr_src) {
  int e = blockIdx.x * 256 + threadIdx.x;
  if (e >= E_TOT) return;
  int s, d;
  if (e < E_EDGES) { s = src[e]; d = dst[e]; } else { s = d = e - E_EDGES; }
  int t = s / TILE_N;
  int pos = offT[d * NT + t] + atomicAdd(&cntT[d * NT + t], 1);
  csr_src[pos] = s;
}

#define BFLY_MAX4(m0, m1, m2, m3)                         \
  _Pragma("unroll") for (int off = 1; off < 64; off <<= 1) { \
    m0 = fmaxf(m0, __shfl_xor(m0, off));                  \
    m1 = fmaxf(m1, __shfl_xor(m1, off));                  \
    m2 = fmaxf(m2, __shfl_xor(m2, off));                  \
    m3 = fmaxf(m3, __shfl_xor(m3, off));                  \
  }
#define BFLY_SUM4(s0, s1, s2, s3)                         \
  _Pragma("unroll") for (int off = 1; off < 64; off <<= 1) { \
    s0 += __shfl_xor(s0, off);                            \
    s1 += __shfl_xor(s1, off);                            \
    s2 += __shfl_xor(s2, off);                            \
    s3 += __shfl_xor(s3, off);                            \
  }

// ---------------------------------------------------------------------------
// Fused softmax + aggregation — V_old structure (151us proven), verbatim.
// One wave per dst node; lane owns 2 feats; head = lane/16. The only R16
// change: the node's edge range comes from the tiled offT (contiguous,
// tile-ordered within the node) -> concurrent waves sweep src tiles in
// correlated order (free L2 temporal-locality shot).
// LAW (R5/R7/R10, re-confirmed R13): every gather instruction's 64 lanes
// cover exactly ONE contiguous h-row span.
// History: R12/R13 quad-row gather (fewer, wider instrs) = 190us; R14
// async 24-deep LDS staging = 200us; R15 per-edge recompute = ~280us.
// Per-wave MLP/instruction-shape changes all LOSE vs this structure.
// ---------------------------------------------------------------------------
__global__ __launch_bounds__(256) void k_aggr(
    const int* __restrict__ offT, const int* __restrict__ csr_src,
    const float* __restrict__ asrc, const float* __restrict__ adst,
    const __half* __restrict__ h, const float* __restrict__ bias,
    const int* __restrict__ batch, float* __restrict__ out_h,
    unsigned* __restrict__ pooled, int do_pool) {
  __shared__ int   sv_lds[4][64];
  __shared__ float w_lds[4][64][4];
  int gid = blockIdx.x * 256 + threadIdx.x;
  int node = gid >> 6, lane = gid & 63, wl = threadIdx.x >> 6;
  if (node >= N_NODES) return;
  int head = lane >> 4;
  int lo = offT[node * NT], hi = offT[node * NT + NT];
  int deg = hi - lo;
  float4 ad4 = ((const float4*)adst)[node];  // broadcast
  float ax = 0.f, ay = 0.f;
  float S;

  if (deg <= 64) {
    int j = lo + lane;
    int sv = (j < hi) ? csr_src[j] : 0;
    float4 a4 = ((const float4*)asrc)[sv];
    bool valid = (j < hi);
    float e0 = valid ? lrelu(a4.x + ad4.x) : -1e30f;
    float e1 = valid ? lrelu(a4.y + ad4.y) : -1e30f;
    float e2 = valid ? lrelu(a4.z + ad4.z) : -1e30f;
    float e3 = valid ? lrelu(a4.w + ad4.w) : -1e30f;
    float m0 = e0, m1 = e1, m2 = e2, m3 = e3;
    BFLY_MAX4(m0, m1, m2, m3)
    float w0 = expf(e0 - m0), w1 = expf(e1 - m1);
    float w2 = expf(e2 - m2), w3 = expf(e3 - m3);  // invalid lanes -> 0
    float s0 = w0, s1 = w1, s2 = w2, s3 = w3;
    BFLY_SUM4(s0, s1, s2, s3)
    sv_lds[wl][lane] = sv;
    *(float4*)&w_lds[wl][lane][0] = make_float4(w0, w1, w2, w3);
    S = (head == 0) ? s0 : (head == 1) ? s1 : (head == 2) ? s2 : s3;
    int jj = 0;
    for (; jj + 8 <= deg; jj += 8) {
      int i0 = sv_lds[wl][jj + 0], i1 = sv_lds[wl][jj + 1];
      int i2 = sv_lds[wl][jj + 2], i3 = sv_lds[wl][jj + 3];
      int i4 = sv_lds[wl][jj + 4], i5 = sv_lds[wl][jj + 5];
      int i6 = sv_lds[wl][jj + 6], i7 = sv_lds[wl][jj + 7];
      float wA = w_lds[wl][jj + 0][head], wB = w_lds[wl][jj + 1][head];
      float wC = w_lds[wl][jj + 2][head], wD = w_lds[wl][jj + 3][head];
      float wE = w_lds[wl][jj + 4][head], wF = w_lds[wl][jj + 5][head];
      float wG = w_lds[wl][jj + 6][head], wH = w_lds[wl][jj + 7][head];
      float2 h0 = __half22float2(*(const __half2*)(h + (size_t)i0 * HC + lane * 2));
      float2 h1 = __half22float2(*(const __half2*)(h + (size_t)i1 * HC + lane * 2));
      float2 h2 = __half22float2(*(const __half2*)(h + (size_t)i2 * HC + lane * 2));
      float2 h3 = __half22float2(*(const __half2*)(h + (size_t)i3 * HC + lane * 2));
      float2 h4 = __half22float2(*(const __half2*)(h + (size_t)i4 * HC + lane * 2));
      float2 h5 = __half22float2(*(const __half2*)(h + (size_t)i5 * HC + lane * 2));
      float2 h6 = __half22float2(*(const __half2*)(h + (size_t)i6 * HC + lane * 2));
      float2 h7 = __half22float2(*(const __half2*)(h + (size_t)i7 * HC + lane * 2));
      ax += wA * h0.x; ay += wA * h0.y;
      ax += wB * h1.x; ay += wB * h1.y;
      ax += wC * h2.x; ay += wC * h2.y;
      ax += wD * h3.x; ay += wD * h3.y;
      ax += wE * h4.x; ay += wE * h4.y;
      ax += wF * h5.x; ay += wF * h5.y;
      ax += wG * h6.x; ay += wG * h6.y;
      ax += wH * h7.x; ay += wH * h7.y;
    }
    for (; jj + 4 <= deg; jj += 4) {
      int i0 = sv_lds[wl][jj + 0], i1 = sv_lds[wl][jj + 1];
      int i2 = sv_lds[wl][jj + 2], i3 = sv_lds[wl][jj + 3];
      float wA = w_lds[wl][jj + 0][head], wB = w_lds[wl][jj + 1][head];
      float wC = w_lds[wl][jj + 2][head], wD = w_lds[wl][jj + 3][head];
      float2 h0 = __half22float2(*(const __half2*)(h + (size_t)i0 * HC + lane * 2));
      float2 h1 = __half22float2(*(const __half2*)(h + (size_t)i1 * HC + lane * 2));
      float2 h2 = __half22float2(*(const __half2*)(h + (size_t)i2 * HC + lane * 2));
      float2 h3 = __half22float2(*(const __half2*)(h + (size_t)i3 * HC + lane * 2));
      ax += wA * h0.x; ay += wA * h0.y;
      ax += wB * h1.x; ay += wB * h1.y;
      ax += wC * h2.x; ay += wC * h2.y;
      ax += wD * h3.x; ay += wD * h3.y;
    }
    for (; jj < deg; jj++) {
      int i0 = sv_lds[wl][jj];
      float wA = w_lds[wl][jj][head];
      float2 h0 = __half22float2(*(const __half2*)(h + (size_t)i0 * HC + lane * 2));
      ax += wA * h0.x; ay += wA * h0.y;
    }
  } else {
    // rare generic path (deg > 64): chunked two-pass
    float M0 = -1e30f, M1 = -1e30f, M2 = -1e30f, M3 = -1e30f;
    for (int c = lo; c < hi; c += 64) {
      int j = c + lane;
      int sv = (j < hi) ? csr_src[j] : 0;
      float4 a4 = ((const float4*)asrc)[sv];
      bool valid = (j < hi);
      float e0 = valid ? lrelu(a4.x + ad4.x) : -1e30f;
      float e1 = valid ? lrelu(a4.y + ad4.y) : -1e30f;
      float e2 = valid ? lrelu(a4.z + ad4.z) : -1e30f;
      float e3 = valid ? lrelu(a4.w + ad4.w) : -1e30f;
      BFLY_MAX4(e0, e1, e2, e3)
      M0 = fmaxf(M0, e0); M1 = fmaxf(M1, e1);
      M2 = fmaxf(M2, e2); M3 = fmaxf(M3, e3);
    }
    float S0 = 0.f, S1 = 0.f, S2 = 0.f, S3 = 0.f;
    for (int c = lo; c < hi; c += 64) {
      int j = c + lane;
      int sv = (j < hi) ? csr_src[j] : 0;
      float4 a4 = ((const float4*)asrc)[sv];
      bool valid = (j < hi);
      float e0 = valid ? lrelu(a4.x + ad4.x) : -1e30f;
      float e1 = valid ? lrelu(a4.y + ad4.y) : -1e30f;
      float e2 = valid ? lrelu(a4.z + ad4.z) : -1e30f;
      float e3 = valid ? lrelu(a4.w + ad4.w) : -1e30f;
      float w0 = expf(e0 - M0), w1 = expf(e1 - M1);
      float w2 = expf(e2 - M2), w3 = expf(e3 - M3);
      float s0 = w0, s1 = w1, s2 = w2, s3 = w3;
      BFLY_SUM4(s0, s1, s2, s3)
      S0 += s0; S1 += s1; S2 += s2; S3 += s3;
      sv_lds[wl][lane] = sv;
      *(float4*)&w_lds[wl][lane][0] = make_float4(w0, w1, w2, w3);
      int cnt = (hi - c < 64) ? (hi - c) : 64;
      int jj = 0;
      for (; jj + 4 <= cnt; jj += 4) {
        int i0 = sv_lds[wl][jj + 0], i1 = sv_lds[wl][jj + 1];
        int i2 = sv_lds[wl][jj + 2], i3 = sv_lds[wl][jj + 3];
        float wA = w_lds[wl][jj + 0][head], wB = w_lds[wl][jj + 1][head];
        float wC = w_lds[wl][jj + 2][head], wD = w_lds[wl][jj + 3][head];
        float2 h0 = __half22float2(*(const __half2*)(h + (size_t)i0 * HC + lane * 2));
        float2 h1 = __half22float2(*(const __half2*)(h + (size_t)i1 * HC + lane * 2));
        float2 h2 = __half22float2(*(const __half2*)(h + (size_t)i2 * HC + lane * 2));
        float2 h3 = __half22float2(*(const __half2*)(h + (size_t)i3 * HC + lane * 2));
        ax += wA * h0.x; ay += wA * h0.y;
        ax += wB * h1.x; ay += wB * h1.y;
        ax += wC * h2.x; ay += wC * h2.y;
        ax += wD * h3.x; ay += wD * h3.y;
      }
      for (; jj < cnt; jj++) {
        int i0 = sv_lds[wl][jj];
        float wA = w_lds[wl][jj][head];
        float2 h0 = __half22float2(*(const __half2*)(h + (size_t)i0 * HC + lane * 2));
        ax += wA * h0.x; ay += wA * h0.y;
      }
    }
    S = (head == 0) ? S0 : (head == 1) ? S1 : (head == 2) ? S2 : S3;
  }

  float rden = 1.f / S;
  float2 b = *(const float2*)(bias + lane * 2);
  float vx = fmaxf(ax * rden + b.x, 0.f);
  float vy = fmaxf(ay * rden + b.y, 0.f);
  *(float2*)(out_h + (size_t)node * HC + lane * 2) = make_float2(vx, vy);
  if (do_pool) {
    int g = batch[node];
    unsigned* pp = pooled + g * HC + lane * 2;
    // post-relu values >= 0: bit compare == float compare; init 0 matches the
    // reference's where(isfinite, pooled, 0) empty-graph guard.
    atomicMax(pp + 0, __float_as_uint(vx));
    atomicMax(pp + 1, __float_as_uint(vy));
  }
}

// final head: out[g] = (pooled[g] @ Wlin + blin) @ Wout + bout ; 1 block/graph
__global__ __launch_bounds__(256) void k_mlp(
    const float* __restrict__ pooled, const float* __restrict__ Wlin,
    const float* __restrict__ blin, const float* __restrict__ Wout,
    const float* __restrict__ bout, float* __restrict__ out) {
  __shared__ float p[HC];
  __shared__ float z[LIN];
  int g = blockIdx.x, tid = threadIdx.x;
  if (tid < HC) p[tid] = pooled[g * HC + tid];
  __syncthreads();
  float zv = blin[tid];
  for (int k = 0; k < HC; k++) zv += p[k] * Wlin[k * LIN + tid];
  z[tid] = zv;
  __syncthreads();
  if (tid < OUTC) {
    float o = bout[tid];
    for (int k = 0; k < LIN; k++) o += z[k] * Wout[k * OUTC + tid];
    out[g * OUTC + tid] = o;
  }
}

extern "C" void kernel_launch(void* const* d_in, const int* in_sizes, int n_in,
                              void* d_out, int out_size, void* d_ws, size_t ws_size,
                              hipStream_t stream) {
  const float* x     = (const float*)d_in[0];
  const int*   ei    = (const int*)d_in[1];
  const int*   batch = (const int*)d_in[2];
  const float* Wl[3] = {(const float*)d_in[3], (const float*)d_in[7], (const float*)d_in[11]};
  const float* As[3] = {(const float*)d_in[4], (const float*)d_in[8], (const float*)d_in[12]};
  const float* Ad[3] = {(const float*)d_in[5], (const float*)d_in[9], (const float*)d_in[13]};
  const float* Bi[3] = {(const float*)d_in[6], (const float*)d_in[10], (const float*)d_in[14]};
  const float* Wlin  = (const float*)d_in[15];
  const float* blin  = (const float*)d_in[16];
  const float* Wout  = (const float*)d_in[17];
  const float* bout  = (const float*)d_in[18];
  float* out = (float*)d_out;

  // workspace layout (float offsets)
  float* ws = (float*)d_ws;
  __half*   h       = (__half*)ws;                 // N*128 halves (3.2M fl)
  float*    nodeB   = ws + 3200000;                // N*128 fp32   (6.4M fl)
  float*    asrc    = ws + 9600000;                // N*4
  float*    adst    = ws + 9800000;                // N*4
  int*      degT    = (int*)(ws + 10000000);       // 250k (adjacent to cntT)
  int*      cntT    = (int*)(ws + 10250000);       // 250k
  int*      offT    = (int*)(ws + 10500000);       // 250001
  int*      csr_src = (int*)(ws + 10750004);       // E_TOT (+pad)
  unsigned* pooled  = (unsigned*)(ws + 11600008);  // 64*128
  int*      bsum    = (int*)(ws + 11608200);       // 245
  int*      boff    = (int*)(ws + 11608456);       // 245

  const int* srcp = ei;
  const int* dstp = ei + E_EDGES;

  hipMemsetAsync(degT, 0, 2 * NSEG * sizeof(int), stream);  // degT + cntT

  // (dst, src_tile)-sorted CSR — built once, reused by all 3 layers
  k_hist<<<(E_TOT + 255) / 256, 256, 0, stream>>>(dstp, srcp, degT);
  k_scanA<<<SCAN_BLOCKS, 256, 0, stream>>>(degT, bsum);
  k_scanB<<<1, 256, 0, stream>>>(bsum, boff, pooled);
  k_scanC<<<SCAN_BLOCKS, 256, 0, stream>>>(degT, boff, offT);
  k_scatter<<<(E_TOT + 255) / 256, 256, 0, stream>>>(srcp, dstp, offT, cntT, csr_src);

  const float* lin_in = x;
  for (int L = 0; L < 3; L++) {
    k_gemm_mfma<<<(N_NODES + 63) / 64, 256, 0, stream>>>(
        lin_in, Wl[L], As[L], Ad[L], h, asrc, adst);
    k_aggr<<<(N_NODES * 64 + 255) / 256, 256, 0, stream>>>(
        offT, csr_src, asrc, adst, h, Bi[L], batch,
        nodeB, pooled, (L == 2) ? 1 : 0);
    lin_in = nodeB;
  }
  k_mlp<<<NG, 256, 0, stream>>>((const float*)pooled, Wlin, blin, Wout, bout, out);
}